// Round 3
// baseline (185.955 us; speedup 1.0000x reference)
//
#include <hip/hip_runtime.h>
#include <hip/hip_bf16.h>

// Problem dims (fixed by setup_inputs):
//   B=4, S=2048, H=1024, NH=16, D=64, M = B*S = 8192
#define S_LEN   2048
#define NHEADS  16
#define HDIM    64
#define HID     1024
#define BATCH   4
#define M_ROWS  (BATCH * S_LEN)   // 8192

typedef __attribute__((ext_vector_type(8))) short short8;
typedef __attribute__((ext_vector_type(4))) float floatx4;   // clang vector (NT-builtin OK)
typedef __attribute__((ext_vector_type(4))) unsigned short ushort4v;

__device__ __forceinline__ unsigned short f2bf_rne(float x) {
  union { float f; unsigned u; } v; v.f = x;
  unsigned r = v.u + 0x7fffu + ((v.u >> 16) & 1u);
  return (unsigned short)(r >> 16);
}

__device__ __forceinline__ float bf2f(unsigned short u) {
  union { unsigned u; float f; } c; c.u = ((unsigned)u) << 16;
  return c.f;
}

__device__ __forceinline__ void glds16(const unsigned short* g, unsigned short* l) {
  __builtin_amdgcn_global_load_lds(
      (const __attribute__((address_space(1))) unsigned int*)g,
      (__attribute__((address_space(3))) unsigned int*)l, 16, 0, 0);
}

// ---------------- fp32 -> bf16 cast, all 4 tensors in one dispatch ----------
#define HS4 (M_ROWS * HID / 4)        // 2097152
#define W4  (HID * HID / 4)           // 262144
__global__ __launch_bounds__(256) void cast_all(
    const float* __restrict__ hs, const float* __restrict__ Wq,
    const float* __restrict__ Wk, const float* __restrict__ Wv,
    unsigned short* __restrict__ hsb, unsigned short* __restrict__ wqb,
    unsigned short* __restrict__ wkb, unsigned short* __restrict__ wvb) {
  int idx = blockIdx.x * 256 + threadIdx.x;
  const float* in;
  unsigned short* out;
  int off;
  if (idx < HS4) {
    in = hs; out = hsb; off = idx;
  } else {
    int r = idx - HS4;
    int seg = r >> 18;          // W4 = 2^18
    off = r & (W4 - 1);
    in  = (seg == 0) ? Wq  : (seg == 1) ? Wk  : Wv;
    out = (seg == 0) ? wqb : (seg == 1) ? wkb : wvb;
  }
  // fp32 inputs are read exactly once -> non-temporal (don't pollute L2)
  floatx4 v = __builtin_nontemporal_load((const floatx4*)in + off);
  ushort4v o;
  o.x = f2bf_rne(v.x);
  o.y = f2bf_rne(v.y);
  o.z = f2bf_rne(v.z);
  o.w = f2bf_rne(v.w);
  ((ushort4v*)out)[off] = o;
}

// ---------------- QKV projection GEMM (phase-split counted-vmcnt pipeline) -
// C[m,n] = bf16(sum_k A[m,k]*W[n,k] + bias[n]); A: MxK bf16, W: NxK bf16.
// Tile 256x128, BK=64, 512 threads = 8 waves (4M x 2N), per-wave 64x64 via
// 4x4 MFMA 16x16x32 fragments.
// R3 change (only the sync structure; dataflow identical to R2):
// per K-tile, TWO fine phases (one per kk substep), m201-style:
//   { stage-issue(3 glds) + 8 ds_read_b128  -> s_barrier
//     -> lgkmcnt(0)+sched_barrier(0) -> setprio(1) 16xMFMA setprio(0) }
// ds_reads stay in flight ACROSS the phase barrier; vmcnt is counted (6)
// once per K-tile, never drained to 0 in the main loop.
// Race safety: buffer (t+2)%3 == buffer (t-1)%3 is only written after the
// iteration-start barrier, which every wave reaches only after its last
// tile-(t-1) ds_reads were drained by the phase lgkmcnt(0).
// Block->work map (R2, verified: FETCH 49MB): each XCD-round covers a
// 4-mtile x 8-slab superblock -> A(2MB)+Wz(2MB) fits the 4MB per-XCD L2.
__global__ __launch_bounds__(512, 2) void qkv_gemm(
    const unsigned short* __restrict__ A,
    const unsigned short* __restrict__ W0, const unsigned short* __restrict__ W1,
    const unsigned short* __restrict__ W2,
    const float* __restrict__ b0, const float* __restrict__ b1,
    const float* __restrict__ b2,
    unsigned short* __restrict__ O0, unsigned short* __restrict__ O1,
    unsigned short* __restrict__ O2) {
  const int K = HID;
  const int N = HID;

  __shared__ __align__(16) unsigned short lds[3 * 24576];  // 3 x 48 KB

  const int tid = threadIdx.x;
  const int w = tid >> 6;          // 0..7
  const int lane = tid & 63;

  // XCD-local superblock mapping (verified R2).
  const int bid = blockIdx.x;
  const int xcd = bid & 7;
  const int rr  = bid >> 3;        // 0..95
  const int sb  = rr >> 5;         // 0..2  XCD-round
  const int q   = rr & 31;
  const int sbid = xcd * 3 + sb;   // 0..23
  const int mg = sbid & 7;
  const int sg = sbid >> 3;
  const int mi   = mg * 4 + (q & 3);    // 0..31
  const int slab = sg * 8 + (q >> 2);   // 0..23 = z*8 + ni
  const int ni = slab & 7;
  const int z  = slab >> 3;
  const int m0 = mi << 8;
  const int n0 = ni << 7;

  const unsigned short* __restrict__ Wz = (z == 0) ? W0 : (z == 1) ? W1 : W2;
  const float* __restrict__ bias = (z == 0) ? b0 : (z == 1) ? b1 : b2;
  unsigned short* __restrict__ O = (z == 0) ? O0 : (z == 1) ? O1 : O2;

  // staging: per K-tile 48 KB = 48 segments of 1 KB (8 rows x 8 chunks of
  // 16B). Wave w owns segments w*6+u. Lane l -> row lr=l>>3, LDS chunk l&7,
  // global chunk (l&7)^lr (XOR swizzle on the SOURCE side, LDS linear).
  const int lr = lane >> 3;
  const int ccs = (lane & 7) ^ lr;
  const unsigned short* gsrc[6];
  unsigned short* ldst[6];
  #pragma unroll
  for (int u = 0; u < 6; ++u) {
    const int seg = w * 6 + u;
    if (seg < 32) {
      gsrc[u] = A + (size_t)(m0 + seg * 8 + lr) * K + ccs * 8;
      ldst[u] = lds + seg * 512;
    } else {
      gsrc[u] = Wz + (size_t)(n0 + (seg - 32) * 8 + lr) * K + ccs * 8;
      ldst[u] = lds + 16384 + (seg - 32) * 512;
    }
  }

  // half-stage: 3 glds16 per call; 6 per K-tile per thread (vmcnt budget)
  auto stage3 = [&](int t, int h) {
    const int bofs = (t % 3) * 24576;
    const int ko = t * 64;
    #pragma unroll
    for (int u = h * 3; u < h * 3 + 3; ++u)
      glds16(gsrc[u] + ko, ldst[u] + bofs);
  };

  const int lrow = lane & 15;
  const int qd = lane >> 4;              // 0..3
  const int sw = lrow & 7;               // read-side swizzle key (row&7)
  const int wm = w & 3;                  // m quadrant (64 rows)
  const int wn = w >> 2;                 // n half (64 cols)
  const int arow = wm * 64 + lrow;
  const int brow = wn * 64 + lrow;

  floatx4 acc[4][4] = {};

  // prologue: tiles 0 and 1 in flight (12 loads/thread outstanding)
  stage3(0, 0); stage3(0, 1);
  stage3(1, 0); stage3(1, 1);

  for (int t = 0; t < 16; ++t) {
    // own tile-t loads landed (tile t+1's 6 may stay in flight); then the
    // barrier makes ALL waves' tile-t loads visible and licenses the
    // overwrite of buffer (t+2)%3 == (t-1)%3.
    if (t < 15) asm volatile("s_waitcnt vmcnt(6)" ::: "memory");
    else        asm volatile("s_waitcnt vmcnt(0)" ::: "memory");
    __builtin_amdgcn_s_barrier();
    asm volatile("" ::: "memory");

    const unsigned short* Asb = lds + (t % 3) * 24576;
    const unsigned short* Bsb = Asb + 16384;
    const bool pf = (t + 2 < 16);

    #pragma unroll
    for (int kk = 0; kk < 2; ++kk) {
      if (pf) stage3(t + 2, kk);         // issue-early: in flight across phase
      const int cp = (((kk << 2) | qd) ^ sw) << 3;  // swizzled chunk -> shorts
      short8 af[4], bf[4];
      #pragma unroll
      for (int im = 0; im < 4; ++im)
        af[im] = *(const short8*)(Asb + (arow + im * 16) * 64 + cp);
      #pragma unroll
      for (int in = 0; in < 4; ++in)
        bf[in] = *(const short8*)(Bsb + (brow + in * 16) * 64 + cp);
      // pin issue order: reads + stage issued BEFORE the phase barrier
      asm volatile("" ::: "memory");
      __builtin_amdgcn_s_barrier();
      asm volatile("s_waitcnt lgkmcnt(0)" ::: "memory");
      __builtin_amdgcn_sched_barrier(0);
      __builtin_amdgcn_s_setprio(1);
      #pragma unroll
      for (int im = 0; im < 4; ++im)
        #pragma unroll
        for (int in = 0; in < 4; ++in)
          acc[im][in] = __builtin_amdgcn_mfma_f32_16x16x32_bf16(af[im], bf[in], acc[im][in], 0, 0, 0);
      __builtin_amdgcn_s_setprio(0);
    }
  }

  // epilogue: C/D layout col = lane&15, row = quad*4 + r; write bf16
  #pragma unroll
  for (int im = 0; im < 4; ++im) {
    #pragma unroll
    for (int in = 0; in < 4; ++in) {
      const int col = n0 + wn * 64 + in * 16 + lrow;
      const float bb = bias[col];
      #pragma unroll
      for (int r = 0; r < 4; ++r) {
        const int row = m0 + wm * 64 + im * 16 + (qd << 2) + r;
        O[(size_t)row * N + col] = f2bf_rne(acc[im][in][r] + bb);
      }
    }
  }
}

// ---------------- log-sparse attention ----------------
// 8 lanes per query (lane = 8 dims, 16 B bf16 loads), 32 queries per block.
// Two-phase register budget (K+scores+softmax, then V+accumulate).
// XCD-contiguous block swizzle: blocks for one head stay on one XCD's L2.
// Non-temporal output stores: out (32 MB, never re-read) must not evict the
// K/V gather working set from L2.
__global__ __launch_bounds__(256) void logsparse_attn(
    const unsigned short* __restrict__ Q, const unsigned short* __restrict__ K,
    const unsigned short* __restrict__ V, const float* __restrict__ mask,
    float* __restrict__ out) {
  // 4096 blocks -> XCD x gets contiguous logical range [x*512, (x+1)*512)
  const int bid = (blockIdx.x & 7) * 512 + (blockIdx.x >> 3);
  const int tid = threadIdx.x;
  const int l = tid & 7;
  const int qglob = bid * 32 + (tid >> 3);

  const int i = qglob & (S_LEN - 1);
  const int h = (qglob >> 11) & (NHEADS - 1);
  const int b = qglob >> 15;

  const size_t base = (size_t)b * S_LEN * HID + h * HDIM + l * 8;

  int js[12];
  js[0] = i;
  int nj = 1;
  for (int d = 1; d <= i; d <<= 1) js[nj++] = i - d;
  #pragma unroll
  for (int t = 0; t < 12; ++t)
    if (t >= nj) js[t] = i;   // clamp: valid row, zeroed after mask

  // ---- phase 1: K + Q + mask prefetch, scores, softmax ----
  short8 k8[12];
  #pragma unroll
  for (int t = 0; t < 12; ++t)
    k8[t] = *(const short8*)(K + base + (size_t)js[t] * HID);
  const short8 q8 = *(const short8*)(Q + base + (size_t)i * HID);
  float mk[12];
  #pragma unroll
  for (int t = 0; t < 12; ++t)
    mk[t] = mask[b * S_LEN + js[t]];

  float qf[8];
  #pragma unroll
  for (int e = 0; e < 8; ++e) qf[e] = bf2f((unsigned short)q8[e]);

  float s[12];
  #pragma unroll
  for (int t = 0; t < 12; ++t) {
    float p = 0.f;
    #pragma unroll
    for (int e = 0; e < 8; ++e) p += qf[e] * bf2f((unsigned short)k8[t][e]);
    p += __shfl_xor(p, 1, 64);
    p += __shfl_xor(p, 2, 64);
    p += __shfl_xor(p, 4, 64);
    s[t] = (t < nj) ? (p * 0.125f + mk[t]) : -1e30f;
  }

  float mx = s[0];
  #pragma unroll
  for (int t = 1; t < 12; ++t) mx = fmaxf(mx, s[t]);
  float lsum = 0.f;
  #pragma unroll
  for (int t = 0; t < 12; ++t) { s[t] = __expf(s[t] - mx); lsum += s[t]; }
  const float inv = 1.f / lsum;

  // ---- phase 2: V batch load + accumulate ----
  short8 v8[12];
  #pragma unroll
  for (int t = 0; t < 12; ++t)
    v8[t] = *(const short8*)(V + base + (size_t)js[t] * HID);

  float o[8] = {};
  #pragma unroll
  for (int t = 0; t < 12; ++t) {
    #pragma unroll
    for (int e = 0; e < 8; ++e) o[e] += s[t] * bf2f((unsigned short)v8[t][e]);
  }

  float* op = out + base + (size_t)i * HID;
  floatx4 o0 = {o[0] * inv, o[1] * inv, o[2] * inv, o[3] * inv};
  floatx4 o1 = {o[4] * inv, o[5] * inv, o[6] * inv, o[7] * inv};
  __builtin_nontemporal_store(o0, (floatx4*)op);
  __builtin_nontemporal_store(o1, (floatx4*)(op + 4));
}

// ---------------- launch ----------------
extern "C" void kernel_launch(void* const* d_in, const int* in_sizes, int n_in,
                              void* d_out, int out_size, void* d_ws, size_t ws_size,
                              hipStream_t stream) {
  const float* hs   = (const float*)d_in[0];
  const float* mask = (const float*)d_in[1];
  const float* Wq   = (const float*)d_in[2];
  const float* bq   = (const float*)d_in[3];
  const float* Wk   = (const float*)d_in[4];
  const float* bk   = (const float*)d_in[5];
  const float* Wv   = (const float*)d_in[6];
  const float* bv   = (const float*)d_in[7];
  float* out = (float*)d_out;

  // workspace layout (all bf16)
  unsigned short* hsb = (unsigned short*)d_ws;                  // M*H
  unsigned short* wqb = hsb + (size_t)M_ROWS * HID;             // H*H
  unsigned short* wkb = wqb + (size_t)HID * HID;
  unsigned short* wvb = wkb + (size_t)HID * HID;
  unsigned short* Qb = wvb + (size_t)HID * HID;                 // M*H
  unsigned short* Kb = Qb + (size_t)M_ROWS * HID;
  unsigned short* Vb = Kb + (size_t)M_ROWS * HID;

  // casts: one dispatch for hs + Wq + Wk + Wv
  {
    int quads = HS4 + 3 * W4;                 // 2883584
    cast_all<<<quads / 256, 256, 0, stream>>>(hs, Wq, Wk, Wv, hsb, wqb, wkb, wvb);
  }

  // QKV projections: 256x128 tiles -> 768 blocks = 3 rounds of 1 block/CU
  {
    qkv_gemm<<<768, 512, 0, stream>>>(hsb, wqb, wkb, wvb, bq, bk, bv, Qb, Kb, Vb);
  }

  // sparse attention: 32 queries per 256-thread block
  {
    int blocks = (BATCH * NHEADS * S_LEN) / 32;   // 4096
    logsparse_attn<<<blocks, 256, 0, stream>>>(Qb, Kb, Vb, mask, out);
  }
}

// Round 4
// 183.881 us; speedup vs baseline: 1.0113x; 1.0113x over previous
//
#include <hip/hip_runtime.h>
#include <hip/hip_bf16.h>

// Problem dims (fixed by setup_inputs):
//   B=4, S=2048, H=1024, NH=16, D=64, M = B*S = 8192
#define S_LEN   2048
#define NHEADS  16
#define HDIM    64
#define HID     1024
#define BATCH   4
#define M_ROWS  (BATCH * S_LEN)   // 8192

typedef __attribute__((ext_vector_type(8))) short short8;
typedef __attribute__((ext_vector_type(4))) float floatx4;   // clang vector (NT-builtin OK)
typedef __attribute__((ext_vector_type(4))) unsigned short ushort4v;

__device__ __forceinline__ unsigned short f2bf_rne(float x) {
  union { float f; unsigned u; } v; v.f = x;
  unsigned r = v.u + 0x7fffu + ((v.u >> 16) & 1u);
  return (unsigned short)(r >> 16);
}

__device__ __forceinline__ float bf2f(unsigned short u) {
  union { unsigned u; float f; } c; c.u = ((unsigned)u) << 16;
  return c.f;
}

__device__ __forceinline__ void glds16(const unsigned short* g, unsigned short* l) {
  __builtin_amdgcn_global_load_lds(
      (const __attribute__((address_space(1))) unsigned int*)g,
      (__attribute__((address_space(3))) unsigned int*)l, 16, 0, 0);
}

// ---------------- fp32 -> bf16 cast, all 4 tensors in one dispatch ----------
#define HS4 (M_ROWS * HID / 4)        // 2097152
#define W4  (HID * HID / 4)           // 262144
__global__ __launch_bounds__(256) void cast_all(
    const float* __restrict__ hs, const float* __restrict__ Wq,
    const float* __restrict__ Wk, const float* __restrict__ Wv,
    unsigned short* __restrict__ hsb, unsigned short* __restrict__ wqb,
    unsigned short* __restrict__ wkb, unsigned short* __restrict__ wvb) {
  int idx = blockIdx.x * 256 + threadIdx.x;
  const float* in;
  unsigned short* out;
  int off;
  if (idx < HS4) {
    in = hs; out = hsb; off = idx;
  } else {
    int r = idx - HS4;
    int seg = r >> 18;          // W4 = 2^18
    off = r & (W4 - 1);
    in  = (seg == 0) ? Wq  : (seg == 1) ? Wk  : Wv;
    out = (seg == 0) ? wqb : (seg == 1) ? wkb : wvb;
  }
  // fp32 inputs are read exactly once -> non-temporal (don't pollute L2)
  floatx4 v = __builtin_nontemporal_load((const floatx4*)in + off);
  ushort4v o;
  o.x = f2bf_rne(v.x);
  o.y = f2bf_rne(v.y);
  o.z = f2bf_rne(v.z);
  o.w = f2bf_rne(v.w);
  ((ushort4v*)out)[off] = o;
}

// ---------------- QKV projection GEMM (R4: LDS-traffic-reduction geometry) -
// C[m,n] = bf16(sum_k A[m,k]*W[n,k] + bias[n]); A: MxK bf16, W: NxK bf16.
//
// R3 post-mortem: the 64x64-per-wave config is LDS-READ-BW-BOUND:
// 16 waves/CU x 16KB/tile = 256KB/tile @ ~85B/cyc = ~3000cyc/tile (matches
// measured 2980), while MFMA needs only ~1030cyc -> MfmaUtil capped ~35%.
// Fix: per-wave output 128x64 (8x4 frags) halves LDS bytes per FLOP:
// 8 waves x 12KB = 96KB/tile (~1150cyc) vs MFMA ~1030cyc -> balanced.
//
// Geometry: tile 256x256, BK=32, 512 threads = 8 waves (2M x 4N), per-wave
// 128x64 via 8x4 MFMA 16x16x32 fragments (one K-substep per tile).
// Triple-buffered LDS (3 x 32 KB = 96 KB), counted vmcnt(4) (R2 skeleton):
// stage tile t+2 during compute(t); never drain vmcnt to 0 in the loop.
// Race safety: buffer (t+2)%3 == (t-1)%3; top-of-loop lgkmcnt(0) + barrier
// proves all waves drained tile t-1 reads before its buffer is re-staged.
//
// Swizzle (rows are 64B = 4 chunks of 16B now): LDS chunk c of row r holds
// global chunk c^((r>>1)&3); read chunk qd^((r>>1)&3) -> within each 16-lane
// group the 8 bank-groups are hit 2-way max (free, m136).
//
// Grid 32m x 4n x 3z = 384 blocks, 1 block/CU (96KB LDS), 1.5 rounds.
// L2 map: 16-block superblocks (4m x 4n x 1z) = 2MB A + 2MB W = 4MB/XCD-L2.
__global__ __launch_bounds__(512, 2) void qkv_gemm(
    const unsigned short* __restrict__ A,
    const unsigned short* __restrict__ W0, const unsigned short* __restrict__ W1,
    const unsigned short* __restrict__ W2,
    const float* __restrict__ b0, const float* __restrict__ b1,
    const float* __restrict__ b2,
    unsigned short* __restrict__ O0, unsigned short* __restrict__ O1,
    unsigned short* __restrict__ O2) {
  const int K = HID;
  const int N = HID;

  __shared__ __align__(16) unsigned short lds[3 * 16384];  // 3 x 32 KB

  const int tid = threadIdx.x;
  const int w = tid >> 6;          // 0..7
  const int lane = tid & 63;

  // XCD-local superblock mapping: 384 blocks, 24 superblocks of 16.
  // XCD x gets superblocks 3x..3x+2; sbid = (mg, z), q = (mi, ni) inside.
  const int bid = blockIdx.x;
  const int xcd = bid & 7;
  const int rr  = bid >> 3;        // 0..47
  const int sbl = rr >> 4;         // 0..2
  const int q   = rr & 15;
  const int sbid = xcd * 3 + sbl;  // 0..23
  const int mg = sbid & 7;         // 8 m-groups of 4 m-tiles
  const int z  = sbid >> 3;        // 0..2
  const int mi = mg * 4 + (q & 3); // 0..31
  const int ni = q >> 2;           // 0..3
  const int m0 = mi << 8;          // *256
  const int n0 = ni << 8;          // *256

  const unsigned short* __restrict__ Wz = (z == 0) ? W0 : (z == 1) ? W1 : W2;
  const float* __restrict__ bias = (z == 0) ? b0 : (z == 1) ? b1 : b2;
  unsigned short* __restrict__ O = (z == 0) ? O0 : (z == 1) ? O1 : O2;

  // staging: per K-tile 32 KB = 32 segments of 1 KB (16 rows x 4 chunks of
  // 16B). Wave w owns segments w*4+u: segs 0..15 = A (256 rows),
  // segs 16..31 = B (256 rows). Lane l -> row lr=l>>2, LDS chunk l&3,
  // global chunk (l&3)^((lr>>1)&3) (source-side swizzle, LDS stays linear).
  const int lr = lane >> 2;
  const int gc = (lane & 3) ^ ((lr >> 1) & 3);
  const unsigned short* gsrc[4];
  unsigned short* ldst[4];
  #pragma unroll
  for (int u = 0; u < 4; ++u) {
    const int seg = w * 4 + u;
    if (seg < 16) {
      gsrc[u] = A + (size_t)(m0 + seg * 16 + lr) * K + gc * 8;
    } else {
      gsrc[u] = Wz + (size_t)(n0 + (seg - 16) * 16 + lr) * K + gc * 8;
    }
    ldst[u] = lds + seg * 512;
  }

  // stage one K-tile: 4 glds16 per thread (vmcnt budget = 4/tile)
  auto stage = [&](int t) {
    const int bofs = (t % 3) * 16384;
    const int ko = t * 32;
    #pragma unroll
    for (int u = 0; u < 4; ++u)
      glds16(gsrc[u] + ko, ldst[u] + bofs);
  };

  const int lrow = lane & 15;
  const int qd = lane >> 4;                    // 0..3
  const int cp = (qd ^ ((lrow >> 1) & 3)) * 8; // swizzled chunk -> shorts
  const int wm = w & 1;                        // m half (128 rows)
  const int wn = w >> 1;                       // n quarter (64 cols)
  const int arow = wm * 128 + lrow;
  const int brow = wn * 64 + lrow;

  floatx4 acc[8][4] = {};

  // prologue: tiles 0 and 1 in flight (8 loads/thread outstanding)
  stage(0);
  stage(1);

  for (int t = 0; t < 32; ++t) {
    // my ds_reads of tile t-1 fully drained before anyone may overwrite
    asm volatile("s_waitcnt lgkmcnt(0)" ::: "memory");
    // counted wait: tile t landed; tile t+1's 4 loads may stay in flight
    if (t < 31) asm volatile("s_waitcnt vmcnt(4)" ::: "memory");
    else        asm volatile("s_waitcnt vmcnt(0)" ::: "memory");
    __builtin_amdgcn_s_barrier();
    asm volatile("" ::: "memory");

    const unsigned short* Asb = lds + (t % 3) * 16384;
    const unsigned short* Bsb = Asb + 8192;

    if (t + 2 < 32) stage(t + 2);      // issue-early: hides under MFMA

    short8 af[8], bf[4];
    #pragma unroll
    for (int im = 0; im < 8; ++im)
      af[im] = *(const short8*)(Asb + (arow + im * 16) * 32 + cp);
    #pragma unroll
    for (int in = 0; in < 4; ++in)
      bf[in] = *(const short8*)(Bsb + (brow + in * 16) * 32 + cp);

    __builtin_amdgcn_s_setprio(1);
    #pragma unroll
    for (int im = 0; im < 8; ++im)
      #pragma unroll
      for (int in = 0; in < 4; ++in)
        acc[im][in] = __builtin_amdgcn_mfma_f32_16x16x32_bf16(af[im], bf[in], acc[im][in], 0, 0, 0);
    __builtin_amdgcn_s_setprio(0);
  }

  // epilogue: C/D layout col = lane&15, row = quad*4 + r; write bf16
  #pragma unroll
  for (int im = 0; im < 8; ++im) {
    #pragma unroll
    for (int in = 0; in < 4; ++in) {
      const int col = n0 + wn * 64 + in * 16 + lrow;
      const float bb = bias[col];
      #pragma unroll
      for (int r = 0; r < 4; ++r) {
        const int row = m0 + wm * 128 + im * 16 + (qd << 2) + r;
        O[(size_t)row * N + col] = f2bf_rne(acc[im][in][r] + bb);
      }
    }
  }
}

// ---------------- log-sparse attention ----------------
// 8 lanes per query (lane = 8 dims, 16 B bf16 loads), 32 queries per block.
// Two-phase register budget (K+scores+softmax, then V+accumulate).
// XCD-contiguous block swizzle: blocks for one head stay on one XCD's L2.
// Non-temporal output stores: out (32 MB, never re-read) must not evict the
// K/V gather working set from L2.
__global__ __launch_bounds__(256) void logsparse_attn(
    const unsigned short* __restrict__ Q, const unsigned short* __restrict__ K,
    const unsigned short* __restrict__ V, const float* __restrict__ mask,
    float* __restrict__ out) {
  // 4096 blocks -> XCD x gets contiguous logical range [x*512, (x+1)*512)
  const int bid = (blockIdx.x & 7) * 512 + (blockIdx.x >> 3);
  const int tid = threadIdx.x;
  const int l = tid & 7;
  const int qglob = bid * 32 + (tid >> 3);

  const int i = qglob & (S_LEN - 1);
  const int h = (qglob >> 11) & (NHEADS - 1);
  const int b = qglob >> 15;

  const size_t base = (size_t)b * S_LEN * HID + h * HDIM + l * 8;

  int js[12];
  js[0] = i;
  int nj = 1;
  for (int d = 1; d <= i; d <<= 1) js[nj++] = i - d;
  #pragma unroll
  for (int t = 0; t < 12; ++t)
    if (t >= nj) js[t] = i;   // clamp: valid row, zeroed after mask

  // ---- phase 1: K + Q + mask prefetch, scores, softmax ----
  short8 k8[12];
  #pragma unroll
  for (int t = 0; t < 12; ++t)
    k8[t] = *(const short8*)(K + base + (size_t)js[t] * HID);
  const short8 q8 = *(const short8*)(Q + base + (size_t)i * HID);
  float mk[12];
  #pragma unroll
  for (int t = 0; t < 12; ++t)
    mk[t] = mask[b * S_LEN + js[t]];

  float qf[8];
  #pragma unroll
  for (int e = 0; e < 8; ++e) qf[e] = bf2f((unsigned short)q8[e]);

  float s[12];
  #pragma unroll
  for (int t = 0; t < 12; ++t) {
    float p = 0.f;
    #pragma unroll
    for (int e = 0; e < 8; ++e) p += qf[e] * bf2f((unsigned short)k8[t][e]);
    p += __shfl_xor(p, 1, 64);
    p += __shfl_xor(p, 2, 64);
    p += __shfl_xor(p, 4, 64);
    s[t] = (t < nj) ? (p * 0.125f + mk[t]) : -1e30f;
  }

  float mx = s[0];
  #pragma unroll
  for (int t = 1; t < 12; ++t) mx = fmaxf(mx, s[t]);
  float lsum = 0.f;
  #pragma unroll
  for (int t = 0; t < 12; ++t) { s[t] = __expf(s[t] - mx); lsum += s[t]; }
  const float inv = 1.f / lsum;

  // ---- phase 2: V batch load + accumulate ----
  short8 v8[12];
  #pragma unroll
  for (int t = 0; t < 12; ++t)
    v8[t] = *(const short8*)(V + base + (size_t)js[t] * HID);

  float o[8] = {};
  #pragma unroll
  for (int t = 0; t < 12; ++t) {
    #pragma unroll
    for (int e = 0; e < 8; ++e) o[e] += s[t] * bf2f((unsigned short)v8[t][e]);
  }

  float* op = out + base + (size_t)i * HID;
  floatx4 o0 = {o[0] * inv, o[1] * inv, o[2] * inv, o[3] * inv};
  floatx4 o1 = {o[4] * inv, o[5] * inv, o[6] * inv, o[7] * inv};
  __builtin_nontemporal_store(o0, (floatx4*)op);
  __builtin_nontemporal_store(o1, (floatx4*)(op + 4));
}

// ---------------- launch ----------------
extern "C" void kernel_launch(void* const* d_in, const int* in_sizes, int n_in,
                              void* d_out, int out_size, void* d_ws, size_t ws_size,
                              hipStream_t stream) {
  const float* hs   = (const float*)d_in[0];
  const float* mask = (const float*)d_in[1];
  const float* Wq   = (const float*)d_in[2];
  const float* bq   = (const float*)d_in[3];
  const float* Wk   = (const float*)d_in[4];
  const float* bk   = (const float*)d_in[5];
  const float* Wv   = (const float*)d_in[6];
  const float* bv   = (const float*)d_in[7];
  float* out = (float*)d_out;

  // workspace layout (all bf16)
  unsigned short* hsb = (unsigned short*)d_ws;                  // M*H
  unsigned short* wqb = hsb + (size_t)M_ROWS * HID;             // H*H
  unsigned short* wkb = wqb + (size_t)HID * HID;
  unsigned short* wvb = wkb + (size_t)HID * HID;
  unsigned short* Qb = wvb + (size_t)HID * HID;                 // M*H
  unsigned short* Kb = Qb + (size_t)M_ROWS * HID;
  unsigned short* Vb = Kb + (size_t)M_ROWS * HID;

  // casts: one dispatch for hs + Wq + Wk + Wv
  {
    int quads = HS4 + 3 * W4;                 // 2883584
    cast_all<<<quads / 256, 256, 0, stream>>>(hs, Wq, Wk, Wv, hsb, wqb, wkb, wvb);
  }

  // QKV projections: 256x256 tiles -> 32 x 4 x 3 = 384 blocks
  {
    qkv_gemm<<<384, 512, 0, stream>>>(hsb, wqb, wkb, wvb, bq, bk, bv, Qb, Kb, Vb);
  }

  // sparse attention: 32 queries per 256-thread block
  {
    int blocks = (BATCH * NHEADS * S_LEN) / 32;   // 4096
    logsparse_attn<<<blocks, 256, 0, stream>>>(Qb, Kb, Vb, mask, out);
  }
}

// Round 5
// 180.234 us; speedup vs baseline: 1.0317x; 1.0202x over previous
//
#include <hip/hip_runtime.h>
#include <hip/hip_bf16.h>

// Problem dims (fixed by setup_inputs):
//   B=4, S=2048, H=1024, NH=16, D=64, M = B*S = 8192
#define S_LEN   2048
#define NHEADS  16
#define HDIM    64
#define HID     1024
#define BATCH   4
#define M_ROWS  (BATCH * S_LEN)   // 8192

typedef __attribute__((ext_vector_type(8))) short short8;
typedef __attribute__((ext_vector_type(4))) float floatx4;   // clang vector (NT-builtin OK)
typedef __attribute__((ext_vector_type(4))) unsigned short ushort4v;

__device__ __forceinline__ unsigned short f2bf_rne(float x) {
  union { float f; unsigned u; } v; v.f = x;
  unsigned r = v.u + 0x7fffu + ((v.u >> 16) & 1u);
  return (unsigned short)(r >> 16);
}

__device__ __forceinline__ float bf2f(unsigned short u) {
  union { unsigned u; float f; } c; c.u = ((unsigned)u) << 16;
  return c.f;
}

__device__ __forceinline__ void glds16(const unsigned short* g, unsigned short* l) {
  __builtin_amdgcn_global_load_lds(
      (const __attribute__((address_space(1))) unsigned int*)g,
      (__attribute__((address_space(3))) unsigned int*)l, 16, 0, 0);
}

// ---------------- fp32 -> bf16 cast, all 4 tensors in one dispatch ----------
#define HS4 (M_ROWS * HID / 4)        // 2097152
#define W4  (HID * HID / 4)           // 262144
__global__ __launch_bounds__(256) void cast_all(
    const float* __restrict__ hs, const float* __restrict__ Wq,
    const float* __restrict__ Wk, const float* __restrict__ Wv,
    unsigned short* __restrict__ hsb, unsigned short* __restrict__ wqb,
    unsigned short* __restrict__ wkb, unsigned short* __restrict__ wvb) {
  int idx = blockIdx.x * 256 + threadIdx.x;
  const float* in;
  unsigned short* out;
  int off;
  if (idx < HS4) {
    in = hs; out = hsb; off = idx;
  } else {
    int r = idx - HS4;
    int seg = r >> 18;          // W4 = 2^18
    off = r & (W4 - 1);
    in  = (seg == 0) ? Wq  : (seg == 1) ? Wk  : Wv;
    out = (seg == 0) ? wqb : (seg == 1) ? wkb : wvb;
  }
  // fp32 inputs are read exactly once -> non-temporal (don't pollute L2)
  floatx4 v = __builtin_nontemporal_load((const floatx4*)in + off);
  ushort4v o;
  o.x = f2bf_rne(v.x);
  o.y = f2bf_rne(v.y);
  o.z = f2bf_rne(v.z);
  o.w = f2bf_rne(v.w);
  ((ushort4v*)out)[off] = o;
}

// ---------------- QKV projection GEMM (R5: R4 geometry + R2 grid/occup.) ---
// C[m,n] = bf16(sum_k A[m,k]*W[n,k] + bias[n]); A: MxK bf16, W: NxK bf16.
//
// Evidence so far:
//  R3: 64x64/wave is LDS-traffic-bound (~2980cyc/K-tile matches wall clock).
//  R4: 128x64/wave (0.75x LDS bytes/FLOP) verified correct, but 384-block
//      grid tail (1.5 rounds) + 1 block/CU cost more than the traffic saved.
// R5 combines the verified pieces:
//  - tile 256x128, 256 threads = 4 waves (2M x 2N), per-wave 128x64 via
//    8x4 MFMA 16x16x32 fragments (R4's verified math)
//  - BK=32, triple-buffered LDS 3x24KB = 72KB -> 2 blocks/CU co-resident
//    (cross-block wave overlap hides barrier/vmcnt stalls, m114)
//  - grid 32m x 8n x 3z = 768 blocks = exactly 3 blocks/CU, no tail
//  - R2's verified counted-vmcnt skeleton (6 glds/thread/tile -> vmcnt(6))
//  - R2's verified L2 superblock map (4m x 8n x 1z per 32-block XCD group)
// Swizzle (64B rows = 4 chunks of 16B): LDS chunk c of row r holds global
// chunk c^((r>>1)&3); read chunk qd^((row>>1)&3) -> 2-way max (free, m136).
// Race safety: buffer (t+2)%3 == (t-1)%3; top-of-loop lgkmcnt(0) + barrier
// proves all waves drained tile t-1 reads before its buffer is re-staged.
__global__ __launch_bounds__(256, 2) void qkv_gemm(
    const unsigned short* __restrict__ A,
    const unsigned short* __restrict__ W0, const unsigned short* __restrict__ W1,
    const unsigned short* __restrict__ W2,
    const float* __restrict__ b0, const float* __restrict__ b1,
    const float* __restrict__ b2,
    unsigned short* __restrict__ O0, unsigned short* __restrict__ O1,
    unsigned short* __restrict__ O2) {
  const int K = HID;
  const int N = HID;

  __shared__ __align__(16) unsigned short lds[3 * 12288];  // 3 x 24 KB

  const int tid = threadIdx.x;
  const int w = tid >> 6;          // 0..3
  const int lane = tid & 63;

  // XCD-local superblock mapping (verified R2: FETCH 49MB).
  const int bid = blockIdx.x;
  const int xcd = bid & 7;
  const int rr  = bid >> 3;        // 0..95
  const int sb  = rr >> 5;         // 0..2  XCD-round
  const int q   = rr & 31;
  const int sbid = xcd * 3 + sb;   // 0..23
  const int mg = sbid & 7;
  const int sg = sbid >> 3;
  const int mi   = mg * 4 + (q & 3);    // 0..31
  const int slab = sg * 8 + (q >> 2);   // 0..23 = z*8 + ni
  const int ni = slab & 7;
  const int z  = slab >> 3;
  const int m0 = mi << 8;          // *256
  const int n0 = ni << 7;          // *128

  const unsigned short* __restrict__ Wz = (z == 0) ? W0 : (z == 1) ? W1 : W2;
  const float* __restrict__ bias = (z == 0) ? b0 : (z == 1) ? b1 : b2;
  unsigned short* __restrict__ O = (z == 0) ? O0 : (z == 1) ? O1 : O2;

  // staging: per K-tile 24 KB = 24 segments of 1 KB (16 rows x 4 chunks of
  // 16B). Wave w owns segments w*6+u (u=0..5): segs 0..15 = A (256 rows),
  // segs 16..23 = B (128 rows). Lane l -> row lr=l>>2, LDS chunk l&3,
  // global chunk (l&3)^((lr>>1)&3) (source-side swizzle, LDS stays linear).
  const int lr = lane >> 2;
  const int gc = (lane & 3) ^ ((lr >> 1) & 3);
  const unsigned short* gsrc[6];
  unsigned short* ldst[6];
  #pragma unroll
  for (int u = 0; u < 6; ++u) {
    const int seg = w * 6 + u;
    if (seg < 16) {
      gsrc[u] = A + (size_t)(m0 + seg * 16 + lr) * K + gc * 8;
    } else {
      gsrc[u] = Wz + (size_t)(n0 + (seg - 16) * 16 + lr) * K + gc * 8;
    }
    ldst[u] = lds + seg * 512;
  }

  // stage one K-tile: 6 glds16 per thread (vmcnt budget = 6/tile)
  auto stage = [&](int t) {
    const int bofs = (t % 3) * 12288;
    const int ko = t * 32;
    #pragma unroll
    for (int u = 0; u < 6; ++u)
      glds16(gsrc[u] + ko, ldst[u] + bofs);
  };

  const int lrow = lane & 15;
  const int qd = lane >> 4;                    // 0..3
  const int cp = (qd ^ ((lrow >> 1) & 3)) * 8; // swizzled chunk -> shorts
  const int wm = w & 1;                        // m half (128 rows)
  const int wn = w >> 1;                       // n half (64 cols)
  const int arow = wm * 128 + lrow;
  const int brow = wn * 64 + lrow;

  floatx4 acc[8][4] = {};

  // prologue: tiles 0 and 1 in flight (12 loads/thread outstanding)
  stage(0);
  stage(1);

  for (int t = 0; t < 32; ++t) {
    // my ds_reads of tile t-1 fully drained before anyone may overwrite
    asm volatile("s_waitcnt lgkmcnt(0)" ::: "memory");
    // counted wait: tile t landed; tile t+1's 6 loads may stay in flight
    if (t < 31) asm volatile("s_waitcnt vmcnt(6)" ::: "memory");
    else        asm volatile("s_waitcnt vmcnt(0)" ::: "memory");
    __builtin_amdgcn_s_barrier();
    asm volatile("" ::: "memory");

    const unsigned short* Asb = lds + (t % 3) * 12288;
    const unsigned short* Bsb = Asb + 8192;

    if (t + 2 < 32) stage(t + 2);      // issue-early: hides under MFMA

    short8 af[8], bf[4];
    #pragma unroll
    for (int im = 0; im < 8; ++im)
      af[im] = *(const short8*)(Asb + (arow + im * 16) * 32 + cp);
    #pragma unroll
    for (int in = 0; in < 4; ++in)
      bf[in] = *(const short8*)(Bsb + (brow + in * 16) * 32 + cp);

    __builtin_amdgcn_s_setprio(1);
    #pragma unroll
    for (int im = 0; im < 8; ++im)
      #pragma unroll
      for (int in = 0; in < 4; ++in)
        acc[im][in] = __builtin_amdgcn_mfma_f32_16x16x32_bf16(af[im], bf[in], acc[im][in], 0, 0, 0);
    __builtin_amdgcn_s_setprio(0);
  }

  // epilogue: C/D layout col = lane&15, row = quad*4 + r; write bf16
  #pragma unroll
  for (int im = 0; im < 8; ++im) {
    #pragma unroll
    for (int in = 0; in < 4; ++in) {
      const int col = n0 + wn * 64 + in * 16 + lrow;
      const float bb = bias[col];
      #pragma unroll
      for (int r = 0; r < 4; ++r) {
        const int row = m0 + wm * 128 + im * 16 + (qd << 2) + r;
        O[(size_t)row * N + col] = f2bf_rne(acc[im][in][r] + bb);
      }
    }
  }
}

// ---------------- log-sparse attention ----------------
// 8 lanes per query (lane = 8 dims, 16 B bf16 loads), 32 queries per block.
// Two-phase register budget (K+scores+softmax, then V+accumulate).
// XCD-contiguous block swizzle: blocks for one head stay on one XCD's L2.
// Non-temporal output stores: out (32 MB, never re-read) must not evict the
// K/V gather working set from L2.
__global__ __launch_bounds__(256) void logsparse_attn(
    const unsigned short* __restrict__ Q, const unsigned short* __restrict__ K,
    const unsigned short* __restrict__ V, const float* __restrict__ mask,
    float* __restrict__ out) {
  // 4096 blocks -> XCD x gets contiguous logical range [x*512, (x+1)*512)
  const int bid = (blockIdx.x & 7) * 512 + (blockIdx.x >> 3);
  const int tid = threadIdx.x;
  const int l = tid & 7;
  const int qglob = bid * 32 + (tid >> 3);

  const int i = qglob & (S_LEN - 1);
  const int h = (qglob >> 11) & (NHEADS - 1);
  const int b = qglob >> 15;

  const size_t base = (size_t)b * S_LEN * HID + h * HDIM + l * 8;

  int js[12];
  js[0] = i;
  int nj = 1;
  for (int d = 1; d <= i; d <<= 1) js[nj++] = i - d;
  #pragma unroll
  for (int t = 0; t < 12; ++t)
    if (t >= nj) js[t] = i;   // clamp: valid row, zeroed after mask

  // ---- phase 1: K + Q + mask prefetch, scores, softmax ----
  short8 k8[12];
  #pragma unroll
  for (int t = 0; t < 12; ++t)
    k8[t] = *(const short8*)(K + base + (size_t)js[t] * HID);
  const short8 q8 = *(const short8*)(Q + base + (size_t)i * HID);
  float mk[12];
  #pragma unroll
  for (int t = 0; t < 12; ++t)
    mk[t] = mask[b * S_LEN + js[t]];

  float qf[8];
  #pragma unroll
  for (int e = 0; e < 8; ++e) qf[e] = bf2f((unsigned short)q8[e]);

  float s[12];
  #pragma unroll
  for (int t = 0; t < 12; ++t) {
    float p = 0.f;
    #pragma unroll
    for (int e = 0; e < 8; ++e) p += qf[e] * bf2f((unsigned short)k8[t][e]);
    p += __shfl_xor(p, 1, 64);
    p += __shfl_xor(p, 2, 64);
    p += __shfl_xor(p, 4, 64);
    s[t] = (t < nj) ? (p * 0.125f + mk[t]) : -1e30f;
  }

  float mx = s[0];
  #pragma unroll
  for (int t = 1; t < 12; ++t) mx = fmaxf(mx, s[t]);
  float lsum = 0.f;
  #pragma unroll
  for (int t = 0; t < 12; ++t) { s[t] = __expf(s[t] - mx); lsum += s[t]; }
  const float inv = 1.f / lsum;

  // ---- phase 2: V batch load + accumulate ----
  short8 v8[12];
  #pragma unroll
  for (int t = 0; t < 12; ++t)
    v8[t] = *(const short8*)(V + base + (size_t)js[t] * HID);

  float o[8] = {};
  #pragma unroll
  for (int t = 0; t < 12; ++t) {
    #pragma unroll
    for (int e = 0; e < 8; ++e) o[e] += s[t] * bf2f((unsigned short)v8[t][e]);
  }

  float* op = out + base + (size_t)i * HID;
  floatx4 o0 = {o[0] * inv, o[1] * inv, o[2] * inv, o[3] * inv};
  floatx4 o1 = {o[4] * inv, o[5] * inv, o[6] * inv, o[7] * inv};
  __builtin_nontemporal_store(o0, (floatx4*)op);
  __builtin_nontemporal_store(o1, (floatx4*)(op + 4));
}

// ---------------- launch ----------------
extern "C" void kernel_launch(void* const* d_in, const int* in_sizes, int n_in,
                              void* d_out, int out_size, void* d_ws, size_t ws_size,
                              hipStream_t stream) {
  const float* hs   = (const float*)d_in[0];
  const float* mask = (const float*)d_in[1];
  const float* Wq   = (const float*)d_in[2];
  const float* bq   = (const float*)d_in[3];
  const float* Wk   = (const float*)d_in[4];
  const float* bk   = (const float*)d_in[5];
  const float* Wv   = (const float*)d_in[6];
  const float* bv   = (const float*)d_in[7];
  float* out = (float*)d_out;

  // workspace layout (all bf16)
  unsigned short* hsb = (unsigned short*)d_ws;                  // M*H
  unsigned short* wqb = hsb + (size_t)M_ROWS * HID;             // H*H
  unsigned short* wkb = wqb + (size_t)HID * HID;
  unsigned short* wvb = wkb + (size_t)HID * HID;
  unsigned short* Qb = wvb + (size_t)HID * HID;                 // M*H
  unsigned short* Kb = Qb + (size_t)M_ROWS * HID;
  unsigned short* Vb = Kb + (size_t)M_ROWS * HID;

  // casts: one dispatch for hs + Wq + Wk + Wv
  {
    int quads = HS4 + 3 * W4;                 // 2883584
    cast_all<<<quads / 256, 256, 0, stream>>>(hs, Wq, Wk, Wv, hsb, wqb, wkb, wvb);
  }

  // QKV projections: 256x128 tiles -> 32 x 8 x 3 = 768 blocks, 2 blocks/CU
  {
    qkv_gemm<<<768, 256, 0, stream>>>(hsb, wqb, wkb, wvb, bq, bk, bv, Qb, Kb, Vb);
  }

  // sparse attention: 32 queries per 256-thread block
  {
    int blocks = (BATCH * NHEADS * S_LEN) / 32;   // 4096
    logsparse_attn<<<blocks, 256, 0, stream>>>(Qb, Kb, Vb, mask, out);
  }
}